// Round 4
// baseline (234.022 us; speedup 1.0000x reference)
//
#include <hip/hip_runtime.h>
#include <hip/hip_bf16.h>
#include <stdint.h>

// B=4, T=1024, C=1024, H=16, D=64, ks=16
// wei[b,h,i,j] = cs[i][e(j)] - cs[i][s(j)], s=clip(j-16,0,64), e=clip(j+16,0,64)
// => wei==0 for j>=80; tail folds to one weight * tail[b,:] where
// tail[b,:] = (sum_{j>=80} v[b,j,:]) @ Wv^T  -- V projection only needs j<128.
// R3: V-proj restricted to 128 rows/b; exact fp32 tail via vsum GEMV; fused cvt.

typedef __bf16 bf16x8 __attribute__((ext_vector_type(8)));
typedef float f32x4 __attribute__((ext_vector_type(4)));

#define AS1(p) ((__attribute__((address_space(1))) void*)(p))
#define AS3(p) ((__attribute__((address_space(3))) void*)(p))

// ---------------- fused fp32 -> bf16 convert (float4 per thread) ----------
// y=0:q  y=1:k  y=2..5:Wq,Wk,Wv,Wp  y=6: v rows [0,128) per batch (gather)
__global__ __launch_bounds__(256) void cvt_kernel(
    const float* __restrict__ q, const float* __restrict__ k,
    const float* __restrict__ v, const float* __restrict__ Wq,
    const float* __restrict__ Wk, const float* __restrict__ Wv,
    const float* __restrict__ Wp,
    ushort4* __restrict__ qk_bf, ushort4* __restrict__ w_bf,
    ushort4* __restrict__ vhead_bf)
{
  const int y = blockIdx.y;
  int i = blockIdx.x * 256 + threadIdx.x;
  const float* src; ushort4* dst; int n4; size_t srcIdx;
  if (y < 2) {
    n4 = 1048576; if (i >= n4) return;
    src = y == 0 ? q : k; dst = qk_bf + (size_t)y * 1048576; srcIdx = i;
  } else if (y < 6) {
    n4 = 262144; if (i >= n4) return;
    src = y == 2 ? Wq : y == 3 ? Wk : y == 4 ? Wv : Wp;
    dst = w_bf + (size_t)(y - 2) * 262144; srcIdx = i;
  } else {
    n4 = 131072; if (i >= n4) return;   // 4 b x 128 rows x 256 float4
    int b = i >> 15, rem = i & 32767;
    src = v; dst = vhead_bf; srcIdx = (size_t)b * 262144 + rem;
  }
  float4 val = ((const float4*)src)[srcIdx];
  union { ushort4 u; __hip_bfloat16 h[4]; } c;
  c.h[0] = __float2bfloat16(val.x); c.h[1] = __float2bfloat16(val.y);
  c.h[2] = __float2bfloat16(val.z); c.h[3] = __float2bfloat16(val.w);
  dst[i] = c.u;
}

// ---------------- bf16 NT GEMM tile: 128x128, K=1024, BK=32 ---------------
// A: tile base (128 rows, stride 1024). Bw: weight tile base (128 rows).
// C: output tile base (rows stride 1024, cols 0..127). bias pre-offset.
template <typename OutT>
__device__ __forceinline__ void gemm_tile(
    const __hip_bfloat16* __restrict__ A, const __hip_bfloat16* __restrict__ Bw,
    OutT* __restrict__ C, const float* __restrict__ bias)
{
  const int N = 1024, K = 1024;
  __shared__ __align__(16) __hip_bfloat16 As[128 * 32];
  __shared__ __align__(16) __hip_bfloat16 Bs[128 * 32];
  const int t = threadIdx.x;
  const int wv = t >> 6, lane = t & 63;
  const int wRow = (wv >> 1) * 64, wCol = (wv & 1) * 64;
  const int mrow = lane & 15, kq = lane >> 4;

  f32x4 acc[4][4] = {};

  for (int k0 = 0; k0 < K; k0 += 32) {
    __syncthreads();
#pragma unroll
    for (int tI = 0; tI < 2; ++tI) {
      int chunk = wv * 2 + tI;              // 0..7, 1024B each
      int byteOff = chunk * 1024 + lane * 16;
      int row = byteOff >> 6;
      int colEl = (byteOff & 63) >> 1;
      const __hip_bfloat16* ga = A + (size_t)row * K + k0 + colEl;
      __builtin_amdgcn_global_load_lds(AS1((void*)ga), AS3(&As[chunk * 512]), 16, 0, 0);
      const __hip_bfloat16* gb = Bw + (size_t)row * K + k0 + colEl;
      __builtin_amdgcn_global_load_lds(AS1((void*)gb), AS3(&Bs[chunk * 512]), 16, 0, 0);
    }
    __syncthreads();

    bf16x8 af[4], bf[4];
#pragma unroll
    for (int mi = 0; mi < 4; ++mi)
      af[mi] = *(const bf16x8*)&As[(wRow + mi * 16 + mrow) * 32 + kq * 8];
#pragma unroll
    for (int ni = 0; ni < 4; ++ni)
      bf[ni] = *(const bf16x8*)&Bs[(wCol + ni * 16 + mrow) * 32 + kq * 8];
#pragma unroll
    for (int mi = 0; mi < 4; ++mi)
#pragma unroll
      for (int ni = 0; ni < 4; ++ni)
        acc[mi][ni] = __builtin_amdgcn_mfma_f32_16x16x32_bf16(af[mi], bf[ni], acc[mi][ni], 0, 0, 0);
  }

  // C/D layout: col = lane&15, row = (lane>>4)*4 + r   [m89-verified]
#pragma unroll
  for (int mi = 0; mi < 4; ++mi)
#pragma unroll
    for (int ni = 0; ni < 4; ++ni)
#pragma unroll
      for (int r = 0; r < 4; ++r) {
        int row = wRow + mi * 16 + kq * 4 + r;
        int col = wCol + ni * 16 + mrow;
        float val = acc[mi][ni][r];
        if (bias) val += bias[col];
        if constexpr (__is_same(OutT, __hip_bfloat16))
          C[(size_t)row * N + col] = __float2bfloat16(val);
        else
          C[(size_t)row * N + col] = val;
      }
}

// QK: blocks 0..511 = 2z x 32m x 8n, (z,m) fixed within an XCD (l diff 64 == 0 mod 8)
// V-head: blocks 512..543 = 4b x 8n (128 rows per b).
__global__ __launch_bounds__(256) void qkv_gemm_kernel(
    const __hip_bfloat16* __restrict__ QKbf, const __hip_bfloat16* __restrict__ Wbf,
    const __hip_bfloat16* __restrict__ Vhead,
    __hip_bfloat16* __restrict__ QKp, __hip_bfloat16* __restrict__ VPh)
{
  int l = blockIdx.x;
  if (l < 512) {
    int zm = l & 63, z = zm >> 5, m = zm & 31, n = l >> 6;
    gemm_tile<__hip_bfloat16>(
        QKbf + (size_t)z * 4194304 + (size_t)m * 131072,
        Wbf + (size_t)z * 1048576 + (size_t)n * 131072,
        QKp + (size_t)z * 4194304 + (size_t)m * 131072 + n * 128, nullptr);
  } else {
    int vb = l - 512, b = vb >> 3, n = vb & 7;
    gemm_tile<__hip_bfloat16>(
        Vhead + (size_t)b * 131072,
        Wbf + (size_t)2 * 1048576 + (size_t)n * 131072,
        VPh + (size_t)b * 131072 + n * 128, nullptr);
  }
}

__global__ __launch_bounds__(256) void final_gemm_kernel(
    const __hip_bfloat16* __restrict__ Abf, const __hip_bfloat16* __restrict__ Wpbf,
    float* __restrict__ Out, const float* __restrict__ bias)
{
  int l = blockIdx.x, m = l & 31, n = l >> 5;
  gemm_tile<float>(Abf + (size_t)m * 131072, Wpbf + (size_t)n * 131072,
                   Out + (size_t)m * 131072 + n * 128, bias + n * 128);
}

// ------- vsum partials: partialv[b][jseg][c] = sum of 118 rows of v -------
__global__ __launch_bounds__(256) void vsum_kernel(
    const float* __restrict__ v, float* __restrict__ partialv)
{
  const int cseg = blockIdx.x, jseg = blockIdx.y, b = blockIdx.z;
  const int c = cseg * 256 + threadIdx.x;
  const int jBase = 80 + jseg * 118;          // 944 = 8*118
  float s = 0.0f;
  for (int r = 0; r < 118; ++r)
    s += v[((size_t)(b * 1024 + jBase + r)) * 1024 + c];
  partialv[(size_t)(b * 8 + jseg) * 1024 + c] = s;
}

// ------- tails[b][c] = sum_k vsum[b][k] * Wv[c][k]  (fp32 exact) ----------
// 64 blocks: b = bc>>4, cseg = bc&15 (64 c each); 4 threads per c over k.
__global__ __launch_bounds__(256) void tails_kernel(
    const float* __restrict__ partialv, const float* __restrict__ Wv,
    float* __restrict__ tails)
{
  const int bc = blockIdx.x, b = bc >> 4, cseg = bc & 15;
  const int t = threadIdx.x, cl = t >> 2, kq = t & 3;
  __shared__ float vs[1024];
  for (int idx = t; idx < 1024; idx += 256) {
    float s = 0.0f;
#pragma unroll
    for (int j = 0; j < 8; ++j) s += partialv[(size_t)(b * 8 + j) * 1024 + idx];
    vs[idx] = s;
  }
  __syncthreads();
  const int c = cseg * 64 + cl;
  const float4* wr = (const float4*)(Wv + (size_t)c * 1024);
  const float4* vs4 = (const float4*)vs;
  float acc = 0.0f;
  for (int kk = 0; kk < 64; ++kk) {
    float4 w4 = wr[kq * 64 + kk];
    float4 s4 = vs4[kq * 64 + kk];
    acc += w4.x * s4.x + w4.y * s4.y + w4.z * s4.z + w4.w * s4.w;
  }
  acc += __shfl_xor(acc, 1, 64);
  acc += __shfl_xor(acc, 2, 64);
  if (kq == 0) tails[(size_t)b * 1024 + c] = acc;
}

// ---------------- attention: per (b,h, 64-row i-tile) ---------------------
__global__ __launch_bounds__(256) void attn_kernel(
    const __hip_bfloat16* __restrict__ QP, const __hip_bfloat16* __restrict__ KP,
    const __hip_bfloat16* __restrict__ VPh, const float* __restrict__ tails,
    __hip_bfloat16* __restrict__ OUTA)
{
  const int b = blockIdx.z, h = blockIdx.y, i0 = blockIdx.x * 64;
  const int t = threadIdx.x, lane = t & 63, wv = t >> 6;

  __shared__ float csl[64][65];                        // inclusive cumsum, padded
  __shared__ __align__(16) __hip_bfloat16 wlb[64][96];  // exp(wei-m), A-operand [i][j]
  __shared__ __align__(16) __hip_bfloat16 vpt[64][104]; // vp^T, B-operand [d][j]
  __shared__ float scl[64], tlw[64], tail[64];

  if (t < 64) tail[t] = tails[(size_t)b * 1024 + h * 64 + t];

  // stage vp^T[d][j] for j<80 (compact 128-row layout); zero-pad j=80..95
  for (int idx = t; idx < 80 * 64; idx += 256) {
    int j = idx >> 6, d = idx & 63;
    vpt[d][j] = VPh[((size_t)(b * 128 + j)) * 1024 + h * 64 + d];
  }
  for (int idx = t; idx < 64 * 16; idx += 256) {
    int d = idx >> 4, j = 80 + (idx & 15);
    vpt[d][j] = __float2bfloat16(0.0f);
  }

  // phase A: p = qp*kp/8, inclusive cumsum over d (wave shuffle scan)
  for (int ii = 0; ii < 16; ++ii) {
    int i = wv * 16 + ii;
    size_t row = ((size_t)(b * 1024 + i0 + i)) * 1024 + h * 64 + lane;
    float p = __bfloat162float(QP[row]) * __bfloat162float(KP[row]) * 0.125f;
#pragma unroll
    for (int delta = 1; delta < 64; delta <<= 1) {
      float up = __shfl_up(p, (unsigned)delta, 64);
      if (lane >= delta) p += up;
    }
    csl[i][lane] = p;
  }
  __syncthreads();

  // phase B: wei for j<80, softmax max/sum (tail logit = 0, count 944)
  {
    int i = t >> 2, jg = t & 3;
    float wloc[20];
    float mx = 0.0f;  // includes tail's wei=0
#pragma unroll
    for (int q = 0; q < 20; ++q) {
      int j = jg + 4 * q;
      int s = j - 16; s = s < 0 ? 0 : s;
      int e = j + 16; e = e > 64 ? 64 : e;
      float w = csl[i][e - 1] - (s > 0 ? csl[i][s - 1] : 0.0f);
      wloc[q] = w;
      mx = fmaxf(mx, w);
    }
    mx = fmaxf(mx, __shfl_xor(mx, 1, 64));
    mx = fmaxf(mx, __shfl_xor(mx, 2, 64));
    float sum = 0.0f;
#pragma unroll
    for (int q = 0; q < 20; ++q) {
      float e_ = __expf(wloc[q] - mx);
      wlb[i][jg + 4 * q] = __float2bfloat16(e_);
      sum += e_;
    }
#pragma unroll
    for (int q = 0; q < 4; ++q)      // zero pad j = 80..95
      wlb[i][80 + jg + 4 * q] = __float2bfloat16(0.0f);
    sum += __shfl_xor(sum, 1, 64);
    sum += __shfl_xor(sum, 2, 64);
    float tw = __expf(-mx);
    sum += 944.0f * tw;
    if (jg == 0) { scl[i] = 1.0f / sum; tlw[i] = tw / sum; }
  }
  __syncthreads();

  // phase D: O[i][d] = sum_j wl[i][j] * vpt[d][j] via MFMA (M=64,N=64,K=96)
  {
    const int mh = (wv >> 1) * 32, nh = (wv & 1) * 32;
    const int mrow = lane & 15, kq = lane >> 4;
    f32x4 acc[2][2] = {};
#pragma unroll
    for (int k0 = 0; k0 < 96; k0 += 32) {
      bf16x8 af[2], bf[2];
#pragma unroll
      for (int mi = 0; mi < 2; ++mi)
        af[mi] = *(const bf16x8*)&wlb[mh + mi * 16 + mrow][k0 + kq * 8];
#pragma unroll
      for (int ni = 0; ni < 2; ++ni)
        bf[ni] = *(const bf16x8*)&vpt[nh + ni * 16 + mrow][k0 + kq * 8];
#pragma unroll
      for (int mi = 0; mi < 2; ++mi)
#pragma unroll
        for (int ni = 0; ni < 2; ++ni)
          acc[mi][ni] = __builtin_amdgcn_mfma_f32_16x16x32_bf16(af[mi], bf[ni], acc[mi][ni], 0, 0, 0);
    }
#pragma unroll
    for (int mi = 0; mi < 2; ++mi)
#pragma unroll
      for (int ni = 0; ni < 2; ++ni)
#pragma unroll
        for (int r = 0; r < 4; ++r) {
          int i = mh + mi * 16 + kq * 4 + r;
          int d = nh + ni * 16 + mrow;
          float o = acc[mi][ni][r] * scl[i] + tlw[i] * tail[d];
          OUTA[((size_t)(b * 1024 + i0 + i)) * 1024 + h * 64 + d] = __float2bfloat16(o);
        }
  }
}

// ---------------- launch ---------------------------------------------------
extern "C" void kernel_launch(void* const* d_in, const int* in_sizes, int n_in,
                              void* d_out, int out_size, void* d_ws, size_t ws_size,
                              hipStream_t stream)
{
  (void)in_sizes; (void)n_in; (void)out_size; (void)ws_size;
  const float* q  = (const float*)d_in[0];
  const float* k  = (const float*)d_in[1];
  const float* v  = (const float*)d_in[2];
  const float* Wq = (const float*)d_in[3];
  const float* Wk = (const float*)d_in[4];
  const float* Wv = (const float*)d_in[5];
  const float* Wp = (const float*)d_in[6];
  const float* bp = (const float*)d_in[7];

  char* ws = (char*)d_ws;
  __hip_bfloat16* qk_bf    = (__hip_bfloat16*)(ws);               // 16 MB
  __hip_bfloat16* w_bf     = (__hip_bfloat16*)(ws + 16777216);    // 8 MB
  __hip_bfloat16* vhead_bf = (__hip_bfloat16*)(ws + 25165824);    // 1 MB
  float*          partialv = (float*)(ws + 26214400);             // 128 KB
  float*          tails    = (float*)(ws + 26345472);             // 16 KB
  __hip_bfloat16* QKp      = (__hip_bfloat16*)(ws + 27262976);    // 16 MB (qp,kp)
  __hip_bfloat16* VPh      = (__hip_bfloat16*)(ws + 44040192);    // 1 MB
  __hip_bfloat16* OUTA     = (__hip_bfloat16*)(ws + 45088768);    // 8 MB
  float* out = (float*)d_out;

  cvt_kernel<<<dim3(4096, 7), 256, 0, stream>>>(q, k, v, Wq, Wk, Wv, Wp,
      (ushort4*)qk_bf, (ushort4*)w_bf, (ushort4*)vhead_bf);
  qkv_gemm_kernel<<<dim3(544), 256, 0, stream>>>(qk_bf, w_bf, vhead_bf, QKp, VPh);
  vsum_kernel<<<dim3(4, 8, 4), 256, 0, stream>>>(v, partialv);
  tails_kernel<<<dim3(64), 256, 0, stream>>>(partialv, Wv, tails);
  attn_kernel<<<dim3(16, 16, 4), 256, 0, stream>>>(QKp, QKp + (size_t)4194304,
                                                   VPh, tails, OUTA);
  final_gemm_kernel<<<dim3(256), 256, 0, stream>>>(OUTA, w_bf + (size_t)3 * 1048576,
                                                   out, bp);
}

// Round 5
// 187.388 us; speedup vs baseline: 1.2489x; 1.2489x over previous
//
#include <hip/hip_runtime.h>
#include <hip/hip_bf16.h>
#include <stdint.h>

// B=4, T=1024, C=1024, H=16, D=64, ks=16
// wei[b,h,i,j] = cs[i][e(j)] - cs[i][s(j)], s=clip(j-16,0,64), e=clip(j+16,0,64)
// => wei==0 for j>=80; softmax tail folds into one weight * tail-sum of vp.
// R5: revert to R3 pipeline (768-block qkv = 3/CU co-resident was optimal).
//     BK=64 split-half K-loop (half the barrier drains); final_gemm 512x(64x128)
//     tiles for 2 blocks/CU overlap; single fused cvt launch.

typedef __bf16 bf16x8 __attribute__((ext_vector_type(8)));
typedef float f32x4 __attribute__((ext_vector_type(4)));

#define AS1(p) ((__attribute__((address_space(1))) void*)(p))
#define AS3(p) ((__attribute__((address_space(3))) void*)(p))

// ---------------- fused fp32 -> bf16 convert (float4 per thread) ----------
// flat: idx<3M -> q,k,v (1M float4 each); else -> Wq,Wk,Wv,Wp (256K each)
__global__ __launch_bounds__(256) void cvt_kernel(
    const float* __restrict__ q, const float* __restrict__ k,
    const float* __restrict__ v, const float* __restrict__ Wq,
    const float* __restrict__ Wk, const float* __restrict__ Wv,
    const float* __restrict__ Wp,
    ushort4* __restrict__ qkv_bf, ushort4* __restrict__ w_bf)
{
  int idx = blockIdx.x * 256 + threadIdx.x;
  const float* src; ushort4* dst; int i;
  if (idx < 3145728) {
    int which = idx >> 20; i = idx & 1048575;
    src = which == 0 ? q : which == 1 ? k : v;
    dst = qkv_bf + (size_t)which * 1048576 + i;
  } else {
    int w = idx - 3145728; int which = w >> 18; i = w & 262143;
    src = which == 0 ? Wq : which == 1 ? Wk : which == 2 ? Wv : Wp;
    dst = w_bf + w;
  }
  float4 val = ((const float4*)src)[i];
  union { ushort4 u; __hip_bfloat16 h[4]; } c;
  c.h[0] = __float2bfloat16(val.x); c.h[1] = __float2bfloat16(val.y);
  c.h[2] = __float2bfloat16(val.z); c.h[3] = __float2bfloat16(val.w);
  dst[0] = c.u;
}

// ------- bf16 NT GEMM tile: 128x128, K=1024, BK=64 (two 32-col halves) ----
// A: tile base (128 rows, stride 1024). Bw: weight tile base (128 rows).
// C: output tile base (row stride 1024). bias pre-offset (or null).
template <typename OutT>
__device__ __forceinline__ void gemm_tile128(
    const __hip_bfloat16* __restrict__ A, const __hip_bfloat16* __restrict__ Bw,
    OutT* __restrict__ C, const float* __restrict__ bias)
{
  const int N = 1024, K = 1024;
  __shared__ __align__(16) __hip_bfloat16 As[2][128 * 32];
  __shared__ __align__(16) __hip_bfloat16 Bs[2][128 * 32];
  const int t = threadIdx.x;
  const int wv = t >> 6, lane = t & 63;
  const int wRow = (wv >> 1) * 64, wCol = (wv & 1) * 64;
  const int mrow = lane & 15, kq = lane >> 4;

  f32x4 acc[4][4] = {};

  for (int k0 = 0; k0 < K; k0 += 64) {
    __syncthreads();
#pragma unroll
    for (int half = 0; half < 2; ++half)
#pragma unroll
      for (int tI = 0; tI < 2; ++tI) {
        int chunk = wv * 2 + tI;              // 0..7, 1024B each within half
        int byteOff = chunk * 1024 + lane * 16;
        int row = byteOff >> 6;               // 64B per 32-elem bf16 row
        int colEl = (byteOff & 63) >> 1;
        const __hip_bfloat16* ga = A + (size_t)row * K + k0 + half * 32 + colEl;
        __builtin_amdgcn_global_load_lds(AS1((void*)ga), AS3(&As[half][chunk * 512]), 16, 0, 0);
        const __hip_bfloat16* gb = Bw + (size_t)row * K + k0 + half * 32 + colEl;
        __builtin_amdgcn_global_load_lds(AS1((void*)gb), AS3(&Bs[half][chunk * 512]), 16, 0, 0);
      }
    __syncthreads();

#pragma unroll
    for (int half = 0; half < 2; ++half) {
      bf16x8 af[4], bf[4];
#pragma unroll
      for (int mi = 0; mi < 4; ++mi)
        af[mi] = *(const bf16x8*)&As[half][(wRow + mi * 16 + mrow) * 32 + kq * 8];
#pragma unroll
      for (int ni = 0; ni < 4; ++ni)
        bf[ni] = *(const bf16x8*)&Bs[half][(wCol + ni * 16 + mrow) * 32 + kq * 8];
#pragma unroll
      for (int mi = 0; mi < 4; ++mi)
#pragma unroll
        for (int ni = 0; ni < 4; ++ni)
          acc[mi][ni] = __builtin_amdgcn_mfma_f32_16x16x32_bf16(af[mi], bf[ni], acc[mi][ni], 0, 0, 0);
    }
  }

  // C/D layout: col = lane&15, row = (lane>>4)*4 + r   [m89-verified]
#pragma unroll
  for (int mi = 0; mi < 4; ++mi)
#pragma unroll
    for (int ni = 0; ni < 4; ++ni)
#pragma unroll
      for (int r = 0; r < 4; ++r) {
        int row = wRow + mi * 16 + kq * 4 + r;
        int col = wCol + ni * 16 + mrow;
        float val = acc[mi][ni][r];
        if (bias) val += bias[col];
        if constexpr (__is_same(OutT, __hip_bfloat16))
          C[(size_t)row * N + col] = __float2bfloat16(val);
        else
          C[(size_t)row * N + col] = val;
      }
}

// QKV: 768 blocks = 8n x (3z x 32m); m-consecutive within XCD for A-strip reuse.
__global__ __launch_bounds__(256) void qkv_gemm_kernel(
    const __hip_bfloat16* __restrict__ QKVbf, const __hip_bfloat16* __restrict__ Wbf,
    __hip_bfloat16* __restrict__ QKVp)
{
  int l = blockIdx.x;            // 0..767
  int n = l / 96, mm = l % 96, z = mm >> 5, m = mm & 31;
  gemm_tile128<__hip_bfloat16>(
      QKVbf + (size_t)z * 4194304 + (size_t)m * 131072,
      Wbf + (size_t)z * 1048576 + (size_t)n * 131072,
      QKVp + (size_t)z * 4194304 + (size_t)m * 131072 + n * 128, nullptr);
}

// ------- final GEMM: 64x128 tiles, 512 blocks (2/CU), BK=64 ---------------
__global__ __launch_bounds__(256) void final_gemm_kernel(
    const __hip_bfloat16* __restrict__ Abf, const __hip_bfloat16* __restrict__ Wpbf,
    float* __restrict__ Out, const float* __restrict__ biasAll)
{
  const int N = 1024, K = 1024;
  int l = blockIdx.x;            // 0..511
  int m = l & 63, n = l >> 6;    // m fastest -> XCD A-strip reuse
  const __hip_bfloat16* A = Abf + (size_t)m * 65536;      // 64 rows
  const __hip_bfloat16* Bw = Wpbf + (size_t)n * 131072;   // 128 rows
  float* C = Out + (size_t)m * 65536 + n * 128;
  const float* bias = biasAll + n * 128;

  __shared__ __align__(16) __hip_bfloat16 As[2][64 * 32];
  __shared__ __align__(16) __hip_bfloat16 Bs[2][128 * 32];
  const int t = threadIdx.x;
  const int wv = t >> 6, lane = t & 63;
  const int wRow = (wv >> 1) * 32, wCol = (wv & 1) * 64;
  const int mrow = lane & 15, kq = lane >> 4;

  f32x4 acc[2][4] = {};

  for (int k0 = 0; k0 < K; k0 += 64) {
    __syncthreads();
#pragma unroll
    for (int tI = 0; tI < 6; ++tI) {
      int c = wv * 6 + tI;                     // 0..23 chunks of 1024B
      int byteOff, row, colEl;
      if (c < 8) {                             // A: 2 halves x 4 chunks
        int half = c >> 2, ch = c & 3;
        byteOff = ch * 1024 + lane * 16;
        row = byteOff >> 6; colEl = (byteOff & 63) >> 1;
        const __hip_bfloat16* ga = A + (size_t)row * K + k0 + half * 32 + colEl;
        __builtin_amdgcn_global_load_lds(AS1((void*)ga), AS3(&As[half][ch * 512]), 16, 0, 0);
      } else {                                 // B: 2 halves x 8 chunks
        int cb = c - 8, half = cb >> 3, ch = cb & 7;
        byteOff = ch * 1024 + lane * 16;
        row = byteOff >> 6; colEl = (byteOff & 63) >> 1;
        const __hip_bfloat16* gb = Bw + (size_t)row * K + k0 + half * 32 + colEl;
        __builtin_amdgcn_global_load_lds(AS1((void*)gb), AS3(&Bs[half][ch * 512]), 16, 0, 0);
      }
    }
    __syncthreads();

#pragma unroll
    for (int half = 0; half < 2; ++half) {
      bf16x8 af[2], bf[4];
#pragma unroll
      for (int mi = 0; mi < 2; ++mi)
        af[mi] = *(const bf16x8*)&As[half][(wRow + mi * 16 + mrow) * 32 + kq * 8];
#pragma unroll
      for (int ni = 0; ni < 4; ++ni)
        bf[ni] = *(const bf16x8*)&Bs[half][(wCol + ni * 16 + mrow) * 32 + kq * 8];
#pragma unroll
      for (int mi = 0; mi < 2; ++mi)
#pragma unroll
        for (int ni = 0; ni < 4; ++ni)
          acc[mi][ni] = __builtin_amdgcn_mfma_f32_16x16x32_bf16(af[mi], bf[ni], acc[mi][ni], 0, 0, 0);
    }
  }

#pragma unroll
  for (int mi = 0; mi < 2; ++mi)
#pragma unroll
    for (int ni = 0; ni < 4; ++ni)
#pragma unroll
      for (int r = 0; r < 4; ++r) {
        int row = wRow + mi * 16 + kq * 4 + r;
        int col = wCol + ni * 16 + mrow;
        C[(size_t)row * N + col] = acc[mi][ni][r] + bias[col];
      }
}

// ------- tail partials: partial[bh*16+seg][d] = sum over 59 rows ----------
__global__ __launch_bounds__(256) void tail_partial_kernel(
    const __hip_bfloat16* __restrict__ VP, float* __restrict__ partial)
{
  const int seg = blockIdx.x, bh = blockIdx.y;   // seg 0..15, bh 0..63
  const int b = bh >> 4, h = bh & 15;
  const int d = threadIdx.x & 63, wv = threadIdx.x >> 6;
  const int jBase = 80 + seg * 59;
  float s = 0.0f;
  for (int r = wv; r < 59; r += 4)
    s += __bfloat162float(VP[((size_t)(b * 1024 + jBase + r)) * 1024 + h * 64 + d]);
  __shared__ float red[4][64];
  red[wv][d] = s;
  __syncthreads();
  if (threadIdx.x < 64)
    partial[(bh * 16 + seg) * 64 + threadIdx.x] =
        red[0][threadIdx.x] + red[1][threadIdx.x] + red[2][threadIdx.x] + red[3][threadIdx.x];
}

// ---------------- attention: per (b,h, 64-row i-tile) ---------------------
__global__ __launch_bounds__(256) void attn_kernel(
    const __hip_bfloat16* __restrict__ QP, const __hip_bfloat16* __restrict__ KP,
    const __hip_bfloat16* __restrict__ VP, const float* __restrict__ partial,
    __hip_bfloat16* __restrict__ OUTA)
{
  const int b = blockIdx.z, h = blockIdx.y, i0 = blockIdx.x * 64;
  const int t = threadIdx.x, lane = t & 63, wv = t >> 6;

  __shared__ float csl[64][65];                        // inclusive cumsum, padded
  __shared__ __align__(16) __hip_bfloat16 wlb[64][96];  // exp(wei-m), A-operand [i][j]
  __shared__ __align__(16) __hip_bfloat16 vpt[64][104]; // vp^T, B-operand [d][j]
  __shared__ float scl[64], tlw[64], tail[64];

  // tail reduce for this (b,h)
  if (t < 64) {
    const float* pp = partial + (b * 16 + h) * 16 * 64 + t;
    float s = 0.0f;
#pragma unroll
    for (int seg = 0; seg < 16; ++seg) s += pp[seg * 64];
    tail[t] = s;
  }

  // stage vp^T[d][j] for j<80; zero-pad j=80..95
  for (int idx = t; idx < 80 * 64; idx += 256) {
    int j = idx >> 6, d = idx & 63;
    vpt[d][j] = VP[((size_t)(b * 1024 + j)) * 1024 + h * 64 + d];
  }
  for (int idx = t; idx < 64 * 16; idx += 256) {
    int d = idx >> 4, j = 80 + (idx & 15);
    vpt[d][j] = __float2bfloat16(0.0f);
  }

  // phase A: p = qp*kp/8, inclusive cumsum over d (wave shuffle scan)
  for (int ii = 0; ii < 16; ++ii) {
    int i = wv * 16 + ii;
    size_t row = ((size_t)(b * 1024 + i0 + i)) * 1024 + h * 64 + lane;
    float p = __bfloat162float(QP[row]) * __bfloat162float(KP[row]) * 0.125f;
#pragma unroll
    for (int delta = 1; delta < 64; delta <<= 1) {
      float up = __shfl_up(p, (unsigned)delta, 64);
      if (lane >= delta) p += up;
    }
    csl[i][lane] = p;
  }
  __syncthreads();

  // phase B: wei for j<80, softmax max/sum (tail logit = 0, count 944)
  {
    int i = t >> 2, jg = t & 3;
    float wloc[20];
    float mx = 0.0f;  // includes tail's wei=0
#pragma unroll
    for (int q = 0; q < 20; ++q) {
      int j = jg + 4 * q;
      int s = j - 16; s = s < 0 ? 0 : s;
      int e = j + 16; e = e > 64 ? 64 : e;
      float w = csl[i][e - 1] - (s > 0 ? csl[i][s - 1] : 0.0f);
      wloc[q] = w;
      mx = fmaxf(mx, w);
    }
    mx = fmaxf(mx, __shfl_xor(mx, 1, 64));
    mx = fmaxf(mx, __shfl_xor(mx, 2, 64));
    float sum = 0.0f;
#pragma unroll
    for (int q = 0; q < 20; ++q) {
      float e_ = __expf(wloc[q] - mx);
      wlb[i][jg + 4 * q] = __float2bfloat16(e_);
      sum += e_;
    }
#pragma unroll
    for (int q = 0; q < 4; ++q)      // zero pad j = 80..95
      wlb[i][80 + jg + 4 * q] = __float2bfloat16(0.0f);
    sum += __shfl_xor(sum, 1, 64);
    sum += __shfl_xor(sum, 2, 64);
    float tw = __expf(-mx);
    sum += 944.0f * tw;
    if (jg == 0) { scl[i] = 1.0f / sum; tlw[i] = tw / sum; }
  }
  __syncthreads();

  // phase D: O[i][d] = sum_j wl[i][j] * vpt[d][j] via MFMA (M=64,N=64,K=96)
  {
    const int mh = (wv >> 1) * 32, nh = (wv & 1) * 32;
    const int mrow = lane & 15, kq = lane >> 4;
    f32x4 acc[2][2] = {};
#pragma unroll
    for (int k0 = 0; k0 < 96; k0 += 32) {
      bf16x8 af[2], bf[2];
#pragma unroll
      for (int mi = 0; mi < 2; ++mi)
        af[mi] = *(const bf16x8*)&wlb[mh + mi * 16 + mrow][k0 + kq * 8];
#pragma unroll
      for (int ni = 0; ni < 2; ++ni)
        bf[ni] = *(const bf16x8*)&vpt[nh + ni * 16 + mrow][k0 + kq * 8];
#pragma unroll
      for (int mi = 0; mi < 2; ++mi)
#pragma unroll
        for (int ni = 0; ni < 2; ++ni)
          acc[mi][ni] = __builtin_amdgcn_mfma_f32_16x16x32_bf16(af[mi], bf[ni], acc[mi][ni], 0, 0, 0);
    }
#pragma unroll
    for (int mi = 0; mi < 2; ++mi)
#pragma unroll
      for (int ni = 0; ni < 2; ++ni)
#pragma unroll
        for (int r = 0; r < 4; ++r) {
          int i = mh + mi * 16 + kq * 4 + r;
          int d = nh + ni * 16 + mrow;
          float o = acc[mi][ni][r] * scl[i] + tlw[i] * tail[d];
          OUTA[((size_t)(b * 1024 + i0 + i)) * 1024 + h * 64 + d] = __float2bfloat16(o);
        }
  }
}

// ---------------- launch ---------------------------------------------------
extern "C" void kernel_launch(void* const* d_in, const int* in_sizes, int n_in,
                              void* d_out, int out_size, void* d_ws, size_t ws_size,
                              hipStream_t stream)
{
  (void)in_sizes; (void)n_in; (void)out_size; (void)ws_size;
  const float* q  = (const float*)d_in[0];
  const float* k  = (const float*)d_in[1];
  const float* v  = (const float*)d_in[2];
  const float* Wq = (const float*)d_in[3];
  const float* Wk = (const float*)d_in[4];
  const float* Wv = (const float*)d_in[5];
  const float* Wp = (const float*)d_in[6];
  const float* bp = (const float*)d_in[7];

  char* ws = (char*)d_ws;
  __hip_bfloat16* qkv_bf = (__hip_bfloat16*)(ws);              // 24 MB (q,k,v bf16)
  __hip_bfloat16* w_bf   = (__hip_bfloat16*)(ws + 25165824);   // 8 MB (Wq,Wk,Wv,Wp)
  __hip_bfloat16* QKVp   = (__hip_bfloat16*)(ws + 33554432);   // 24 MB (qp,kp,vp bf16)
  __hip_bfloat16* OUTA   = (__hip_bfloat16*)(ws + 58720256);   // 8 MB
  // tail partials reuse qkv_bf region (dead after qkv_gemm): 64*16*64*4 = 256 KB
  float* partial = (float*)(ws);
  float* out = (float*)d_out;

  cvt_kernel<<<dim3(16384), 256, 0, stream>>>(q, k, v, Wq, Wk, Wv, Wp,
      (ushort4*)qkv_bf, (ushort4*)w_bf);
  qkv_gemm_kernel<<<dim3(768), 256, 0, stream>>>(qkv_bf, w_bf, QKVp);
  tail_partial_kernel<<<dim3(16, 64), 256, 0, stream>>>(QKVp + (size_t)2 * 4194304, partial);
  attn_kernel<<<dim3(16, 16, 4), 256, 0, stream>>>(QKVp, QKVp + (size_t)4194304,
                                                   QKVp + (size_t)2 * 4194304, partial, OUTA);
  final_gemm_kernel<<<dim3(512), 256, 0, stream>>>(OUTA, w_bf + (size_t)3 * 1048576,
                                                   out, bp);
}

// Round 6
// 182.298 us; speedup vs baseline: 1.2837x; 1.0279x over previous
//
#include <hip/hip_runtime.h>
#include <hip/hip_bf16.h>
#include <stdint.h>

// B=4, T=1024, C=1024, H=16, D=64, ks=16
// wei[b,h,i,j] = cs[i][e(j)] - cs[i][s(j)], s=clip(j-16,0,64), e=clip(j+16,0,64)
// => wei==0 for j>=80; softmax tail folds into one weight * tail-sum of vp.
// R6: attn rework -- vectorized 4-thread/row cumsum (serial depth /6), and
// vpt overlays csl LDS after phase B -> ~30KB/block -> 4 blocks/CU, all
// 1024 attn blocks co-resident (no straggler round).

typedef __bf16 bf16x8 __attribute__((ext_vector_type(8)));
typedef float f32x4 __attribute__((ext_vector_type(4)));

#define AS1(p) ((__attribute__((address_space(1))) void*)(p))
#define AS3(p) ((__attribute__((address_space(3))) void*)(p))

// ---------------- fused fp32 -> bf16 convert (float4 per thread) ----------
// flat: idx<3M -> q,k,v (1M float4 each); else -> Wq,Wk,Wv,Wp (256K each)
__global__ __launch_bounds__(256) void cvt_kernel(
    const float* __restrict__ q, const float* __restrict__ k,
    const float* __restrict__ v, const float* __restrict__ Wq,
    const float* __restrict__ Wk, const float* __restrict__ Wv,
    const float* __restrict__ Wp,
    ushort4* __restrict__ qkv_bf, ushort4* __restrict__ w_bf)
{
  int idx = blockIdx.x * 256 + threadIdx.x;
  const float* src; ushort4* dst; int i;
  if (idx < 3145728) {
    int which = idx >> 20; i = idx & 1048575;
    src = which == 0 ? q : which == 1 ? k : v;
    dst = qkv_bf + (size_t)which * 1048576 + i;
  } else {
    int w = idx - 3145728; int which = w >> 18; i = w & 262143;
    src = which == 0 ? Wq : which == 1 ? Wk : which == 2 ? Wv : Wp;
    dst = w_bf + w;
  }
  float4 val = ((const float4*)src)[i];
  union { ushort4 u; __hip_bfloat16 h[4]; } c;
  c.h[0] = __float2bfloat16(val.x); c.h[1] = __float2bfloat16(val.y);
  c.h[2] = __float2bfloat16(val.z); c.h[3] = __float2bfloat16(val.w);
  dst[0] = c.u;
}

// ------- bf16 NT GEMM tile: 128x128, K=1024, BK=64 (two 32-col halves) ----
template <typename OutT>
__device__ __forceinline__ void gemm_tile128(
    const __hip_bfloat16* __restrict__ A, const __hip_bfloat16* __restrict__ Bw,
    OutT* __restrict__ C, const float* __restrict__ bias)
{
  const int N = 1024, K = 1024;
  __shared__ __align__(16) __hip_bfloat16 As[2][128 * 32];
  __shared__ __align__(16) __hip_bfloat16 Bs[2][128 * 32];
  const int t = threadIdx.x;
  const int wv = t >> 6, lane = t & 63;
  const int wRow = (wv >> 1) * 64, wCol = (wv & 1) * 64;
  const int mrow = lane & 15, kq = lane >> 4;

  f32x4 acc[4][4] = {};

  for (int k0 = 0; k0 < K; k0 += 64) {
    __syncthreads();
#pragma unroll
    for (int half = 0; half < 2; ++half)
#pragma unroll
      for (int tI = 0; tI < 2; ++tI) {
        int chunk = wv * 2 + tI;              // 0..7, 1024B each within half
        int byteOff = chunk * 1024 + lane * 16;
        int row = byteOff >> 6;
        int colEl = (byteOff & 63) >> 1;
        const __hip_bfloat16* ga = A + (size_t)row * K + k0 + half * 32 + colEl;
        __builtin_amdgcn_global_load_lds(AS1((void*)ga), AS3(&As[half][chunk * 512]), 16, 0, 0);
        const __hip_bfloat16* gb = Bw + (size_t)row * K + k0 + half * 32 + colEl;
        __builtin_amdgcn_global_load_lds(AS1((void*)gb), AS3(&Bs[half][chunk * 512]), 16, 0, 0);
      }
    __syncthreads();

#pragma unroll
    for (int half = 0; half < 2; ++half) {
      bf16x8 af[4], bf[4];
#pragma unroll
      for (int mi = 0; mi < 4; ++mi)
        af[mi] = *(const bf16x8*)&As[half][(wRow + mi * 16 + mrow) * 32 + kq * 8];
#pragma unroll
      for (int ni = 0; ni < 4; ++ni)
        bf[ni] = *(const bf16x8*)&Bs[half][(wCol + ni * 16 + mrow) * 32 + kq * 8];
#pragma unroll
      for (int mi = 0; mi < 4; ++mi)
#pragma unroll
        for (int ni = 0; ni < 4; ++ni)
          acc[mi][ni] = __builtin_amdgcn_mfma_f32_16x16x32_bf16(af[mi], bf[ni], acc[mi][ni], 0, 0, 0);
    }
  }

  // C/D layout: col = lane&15, row = (lane>>4)*4 + r   [m89-verified]
#pragma unroll
  for (int mi = 0; mi < 4; ++mi)
#pragma unroll
    for (int ni = 0; ni < 4; ++ni)
#pragma unroll
      for (int r = 0; r < 4; ++r) {
        int row = wRow + mi * 16 + kq * 4 + r;
        int col = wCol + ni * 16 + mrow;
        float val = acc[mi][ni][r];
        if (bias) val += bias[col];
        if constexpr (__is_same(OutT, __hip_bfloat16))
          C[(size_t)row * N + col] = __float2bfloat16(val);
        else
          C[(size_t)row * N + col] = val;
      }
}

// QKV: 768 blocks = 8n x (3z x 32m); m-consecutive within XCD for A-strip reuse.
__global__ __launch_bounds__(256) void qkv_gemm_kernel(
    const __hip_bfloat16* __restrict__ QKVbf, const __hip_bfloat16* __restrict__ Wbf,
    __hip_bfloat16* __restrict__ QKVp)
{
  int l = blockIdx.x;            // 0..767
  int n = l / 96, mm = l % 96, z = mm >> 5, m = mm & 31;
  gemm_tile128<__hip_bfloat16>(
      QKVbf + (size_t)z * 4194304 + (size_t)m * 131072,
      Wbf + (size_t)z * 1048576 + (size_t)n * 131072,
      QKVp + (size_t)z * 4194304 + (size_t)m * 131072 + n * 128, nullptr);
}

// ------- final GEMM: 64x128 tiles, 512 blocks (2/CU), BK=64 ---------------
__global__ __launch_bounds__(256) void final_gemm_kernel(
    const __hip_bfloat16* __restrict__ Abf, const __hip_bfloat16* __restrict__ Wpbf,
    float* __restrict__ Out, const float* __restrict__ biasAll)
{
  const int N = 1024, K = 1024;
  int l = blockIdx.x;            // 0..511
  int m = l & 63, n = l >> 6;    // m fastest -> XCD A-strip reuse
  const __hip_bfloat16* A = Abf + (size_t)m * 65536;      // 64 rows
  const __hip_bfloat16* Bw = Wpbf + (size_t)n * 131072;   // 128 rows
  float* C = Out + (size_t)m * 65536 + n * 128;
  const float* bias = biasAll + n * 128;

  __shared__ __align__(16) __hip_bfloat16 As[2][64 * 32];
  __shared__ __align__(16) __hip_bfloat16 Bs[2][128 * 32];
  const int t = threadIdx.x;
  const int wv = t >> 6, lane = t & 63;
  const int wRow = (wv >> 1) * 32, wCol = (wv & 1) * 64;
  const int mrow = lane & 15, kq = lane >> 4;

  f32x4 acc[2][4] = {};

  for (int k0 = 0; k0 < K; k0 += 64) {
    __syncthreads();
#pragma unroll
    for (int tI = 0; tI < 6; ++tI) {
      int c = wv * 6 + tI;                     // 0..23 chunks of 1024B
      int byteOff, row, colEl;
      if (c < 8) {                             // A: 2 halves x 4 chunks
        int half = c >> 2, ch = c & 3;
        byteOff = ch * 1024 + lane * 16;
        row = byteOff >> 6; colEl = (byteOff & 63) >> 1;
        const __hip_bfloat16* ga = A + (size_t)row * K + k0 + half * 32 + colEl;
        __builtin_amdgcn_global_load_lds(AS1((void*)ga), AS3(&As[half][ch * 512]), 16, 0, 0);
      } else {                                 // B: 2 halves x 8 chunks
        int cb = c - 8, half = cb >> 3, ch = cb & 7;
        byteOff = ch * 1024 + lane * 16;
        row = byteOff >> 6; colEl = (byteOff & 63) >> 1;
        const __hip_bfloat16* gb = Bw + (size_t)row * K + k0 + half * 32 + colEl;
        __builtin_amdgcn_global_load_lds(AS1((void*)gb), AS3(&Bs[half][ch * 512]), 16, 0, 0);
      }
    }
    __syncthreads();

#pragma unroll
    for (int half = 0; half < 2; ++half) {
      bf16x8 af[2], bf[4];
#pragma unroll
      for (int mi = 0; mi < 2; ++mi)
        af[mi] = *(const bf16x8*)&As[half][(wRow + mi * 16 + mrow) * 32 + kq * 8];
#pragma unroll
      for (int ni = 0; ni < 4; ++ni)
        bf[ni] = *(const bf16x8*)&Bs[half][(wCol + ni * 16 + mrow) * 32 + kq * 8];
#pragma unroll
      for (int mi = 0; mi < 2; ++mi)
#pragma unroll
        for (int ni = 0; ni < 4; ++ni)
          acc[mi][ni] = __builtin_amdgcn_mfma_f32_16x16x32_bf16(af[mi], bf[ni], acc[mi][ni], 0, 0, 0);
    }
  }

#pragma unroll
  for (int mi = 0; mi < 2; ++mi)
#pragma unroll
    for (int ni = 0; ni < 4; ++ni)
#pragma unroll
      for (int r = 0; r < 4; ++r) {
        int row = wRow + mi * 16 + kq * 4 + r;
        int col = wCol + ni * 16 + mrow;
        C[(size_t)row * N + col] = acc[mi][ni][r] + bias[col];
      }
}

// ------- tail partials: partial[bh*16+seg][d] = sum over 59 rows ----------
__global__ __launch_bounds__(256) void tail_partial_kernel(
    const __hip_bfloat16* __restrict__ VP, float* __restrict__ partial)
{
  const int seg = blockIdx.x, bh = blockIdx.y;   // seg 0..15, bh 0..63
  const int b = bh >> 4, h = bh & 15;
  const int d = threadIdx.x & 63, wv = threadIdx.x >> 6;
  const int jBase = 80 + seg * 59;
  float s = 0.0f;
  for (int r = wv; r < 59; r += 4)
    s += __bfloat162float(VP[((size_t)(b * 1024 + jBase + r)) * 1024 + h * 64 + d]);
  __shared__ float red[4][64];
  red[wv][d] = s;
  __syncthreads();
  if (threadIdx.x < 64)
    partial[(bh * 16 + seg) * 64 + threadIdx.x] =
        red[0][threadIdx.x] + red[1][threadIdx.x] + red[2][threadIdx.x] + red[3][threadIdx.x];
}

// ---------------- attention: per (b,h, 64-row i-tile) ---------------------
// LDS: bufA holds csl (f32 64x68) during phases A/B, then vpt (bf16 64x104)
// for phase D. wlb + scalars separate. ~30.4 KB total -> 4 blocks/CU.
__global__ __launch_bounds__(256) void attn_kernel(
    const __hip_bfloat16* __restrict__ QP, const __hip_bfloat16* __restrict__ KP,
    const __hip_bfloat16* __restrict__ VP, const float* __restrict__ partial,
    __hip_bfloat16* __restrict__ OUTA)
{
  const int b = blockIdx.z, h = blockIdx.y, i0 = blockIdx.x * 64;
  const int t = threadIdx.x, lane = t & 63, wv = t >> 6;

  __shared__ __align__(16) char bufA[64 * 68 * 4];      // csl f32 / vpt bf16 overlay
  float (*csl)[68] = (float(*)[68])bufA;                // inclusive cumsum
  __hip_bfloat16 (*vpt)[104] = (__hip_bfloat16(*)[104])bufA;  // vp^T B-operand
  __shared__ __align__(16) __hip_bfloat16 wlb[64][96];  // exp(wei-m), A-operand [i][j]
  __shared__ float scl[64], tlw[64], tail[64];

  // tail reduce for this (b,h)
  if (t < 64) {
    const float* pp = partial + (b * 16 + h) * 16 * 64 + t;
    float s = 0.0f;
#pragma unroll
    for (int seg = 0; seg < 16; ++seg) s += pp[seg * 64];
    tail[t] = s;
  }

  // phase A: p = qp*kp/8, inclusive cumsum over d.
  // 4 threads per row, 16 elements each: vector loads + register cumsum +
  // 3-shuffle prefix across the 4-lane group + float4 stores.
  {
    const int i = t >> 2, seg = t & 3;
    const size_t base = ((size_t)(b * 1024 + i0 + i)) * 1024 + h * 64 + seg * 16;
    bf16x8 q0 = *(const bf16x8*)(QP + base);
    bf16x8 q1 = *(const bf16x8*)(QP + base + 8);
    bf16x8 k0 = *(const bf16x8*)(KP + base);
    bf16x8 k1 = *(const bf16x8*)(KP + base + 8);
    float cs[16];
    float run = 0.0f;
#pragma unroll
    for (int x = 0; x < 8; ++x) {
      run += (float)q0[x] * (float)k0[x] * 0.125f;
      cs[x] = run;
    }
#pragma unroll
    for (int x = 0; x < 8; ++x) {
      run += (float)q1[x] * (float)k1[x] * 0.125f;
      cs[8 + x] = run;
    }
    float t1 = __shfl_up(run, 1, 4);
    float t2 = __shfl_up(run, 2, 4);
    float t3 = __shfl_up(run, 3, 4);
    float off = 0.0f;
    if (seg > 0) off += t1;
    if (seg > 1) off += t2;
    if (seg > 2) off += t3;
    float4* dst = (float4*)&csl[i][seg * 16];
#pragma unroll
    for (int x4 = 0; x4 < 4; ++x4)
      dst[x4] = make_float4(cs[4 * x4] + off, cs[4 * x4 + 1] + off,
                            cs[4 * x4 + 2] + off, cs[4 * x4 + 3] + off);
  }
  __syncthreads();

  // phase B: wei for j<80, softmax max/sum (tail logit = 0, count 944)
  {
    int i = t >> 2, jg = t & 3;
    float wloc[20];
    float mx = 0.0f;  // includes tail's wei=0
#pragma unroll
    for (int q = 0; q < 20; ++q) {
      int j = jg + 4 * q;
      int s = j - 16; s = s < 0 ? 0 : s;
      int e = j + 16; e = e > 64 ? 64 : e;
      float w = csl[i][e - 1] - (s > 0 ? csl[i][s - 1] : 0.0f);
      wloc[q] = w;
      mx = fmaxf(mx, w);
    }
    mx = fmaxf(mx, __shfl_xor(mx, 1, 64));
    mx = fmaxf(mx, __shfl_xor(mx, 2, 64));
    float sum = 0.0f;
#pragma unroll
    for (int q = 0; q < 20; ++q) {
      float e_ = __expf(wloc[q] - mx);
      wlb[i][jg + 4 * q] = __float2bfloat16(e_);
      sum += e_;
    }
#pragma unroll
    for (int q = 0; q < 4; ++q)      // zero pad j = 80..95
      wlb[i][80 + jg + 4 * q] = __float2bfloat16(0.0f);
    sum += __shfl_xor(sum, 1, 64);
    sum += __shfl_xor(sum, 2, 64);
    float tw = __expf(-mx);
    sum += 944.0f * tw;
    if (jg == 0) { scl[i] = 1.0f / sum; tlw[i] = tw / sum; }
  }
  __syncthreads();   // all csl reads done -> safe to overlay with vpt

  // phase C: stage vp^T[d][j] for j<80; zero-pad j=80..95
  for (int idx = t; idx < 80 * 64; idx += 256) {
    int j = idx >> 6, d = idx & 63;
    vpt[d][j] = VP[((size_t)(b * 1024 + j)) * 1024 + h * 64 + d];
  }
  for (int idx = t; idx < 64 * 16; idx += 256) {
    int d = idx >> 4, j = 80 + (idx & 15);
    vpt[d][j] = __float2bfloat16(0.0f);
  }
  __syncthreads();

  // phase D: O[i][d] = sum_j wl[i][j] * vpt[d][j] via MFMA (M=64,N=64,K=96)
  {
    const int mh = (wv >> 1) * 32, nh = (wv & 1) * 32;
    const int mrow = lane & 15, kq = lane >> 4;
    f32x4 acc[2][2] = {};
#pragma unroll
    for (int k0 = 0; k0 < 96; k0 += 32) {
      bf16x8 af[2], bf[2];
#pragma unroll
      for (int mi = 0; mi < 2; ++mi)
        af[mi] = *(const bf16x8*)&wlb[mh + mi * 16 + mrow][k0 + kq * 8];
#pragma unroll
      for (int ni = 0; ni < 2; ++ni)
        bf[ni] = *(const bf16x8*)&vpt[nh + ni * 16 + mrow][k0 + kq * 8];
#pragma unroll
      for (int mi = 0; mi < 2; ++mi)
#pragma unroll
        for (int ni = 0; ni < 2; ++ni)
          acc[mi][ni] = __builtin_amdgcn_mfma_f32_16x16x32_bf16(af[mi], bf[ni], acc[mi][ni], 0, 0, 0);
    }
#pragma unroll
    for (int mi = 0; mi < 2; ++mi)
#pragma unroll
      for (int ni = 0; ni < 2; ++ni)
#pragma unroll
        for (int r = 0; r < 4; ++r) {
          int i = mh + mi * 16 + kq * 4 + r;
          int d = nh + ni * 16 + mrow;
          float o = acc[mi][ni][r] * scl[i] + tlw[i] * tail[d];
          OUTA[((size_t)(b * 1024 + i0 + i)) * 1024 + h * 64 + d] = __float2bfloat16(o);
        }
  }
}

// ---------------- launch ---------------------------------------------------
extern "C" void kernel_launch(void* const* d_in, const int* in_sizes, int n_in,
                              void* d_out, int out_size, void* d_ws, size_t ws_size,
                              hipStream_t stream)
{
  (void)in_sizes; (void)n_in; (void)out_size; (void)ws_size;
  const float* q  = (const float*)d_in[0];
  const float* k  = (const float*)d_in[1];
  const float* v  = (const float*)d_in[2];
  const float* Wq = (const float*)d_in[3];
  const float* Wk = (const float*)d_in[4];
  const float* Wv = (const float*)d_in[5];
  const float* Wp = (const float*)d_in[6];
  const float* bp = (const float*)d_in[7];

  char* ws = (char*)d_ws;
  __hip_bfloat16* qkv_bf = (__hip_bfloat16*)(ws);              // 24 MB (q,k,v bf16)
  __hip_bfloat16* w_bf   = (__hip_bfloat16*)(ws + 25165824);   // 8 MB (Wq,Wk,Wv,Wp)
  __hip_bfloat16* QKVp   = (__hip_bfloat16*)(ws + 33554432);   // 24 MB (qp,kp,vp bf16)
  __hip_bfloat16* OUTA   = (__hip_bfloat16*)(ws + 58720256);   // 8 MB
  // tail partials reuse qkv_bf region (dead after qkv_gemm): 64*16*64*4 = 256 KB
  float* partial = (float*)(ws);
  float* out = (float*)d_out;

  cvt_kernel<<<dim3(16384), 256, 0, stream>>>(q, k, v, Wq, Wk, Wv, Wp,
      (ushort4*)qkv_bf, (ushort4*)w_bf);
  qkv_gemm_kernel<<<dim3(768), 256, 0, stream>>>(qkv_bf, w_bf, QKVp);
  tail_partial_kernel<<<dim3(16, 64), 256, 0, stream>>>(QKVp + (size_t)2 * 4194304, partial);
  attn_kernel<<<dim3(16, 16, 4), 256, 0, stream>>>(QKVp, QKVp + (size_t)4194304,
                                                   QKVp + (size_t)2 * 4194304, partial, OUTA);
  final_gemm_kernel<<<dim3(512), 256, 0, stream>>>(OUTA, w_bf + (size_t)3 * 1048576,
                                                   out, bp);
}

// Round 7
// 177.867 us; speedup vs baseline: 1.3157x; 1.0249x over previous
//
#include <hip/hip_runtime.h>
#include <hip/hip_bf16.h>
#include <stdint.h>

// B=4, T=1024, C=1024, H=16, D=64, ks=16
// wei[b,h,i,j] = cs[i][e(j)] - cs[i][s(j)], s=clip(j-16,0,64), e=clip(j+16,0,64)
// => wei==0 for j>=80; softmax tail folds into one weight * tail-sum of vp.
// R7: final_gemm 64x64 tiles @1024 blocks (4/CU co-residency);
//     tail folded into qkv epilogue via fp32 atomicAdd (tail_partial deleted).

typedef __bf16 bf16x8 __attribute__((ext_vector_type(8)));
typedef float f32x4 __attribute__((ext_vector_type(4)));

#define AS1(p) ((__attribute__((address_space(1))) void*)(p))
#define AS3(p) ((__attribute__((address_space(3))) void*)(p))

// ---------------- fused fp32 -> bf16 convert (float4 per thread) ----------
// flat: idx<3M -> q,k,v (1M float4 each); else -> Wq,Wk,Wv,Wp (256K each)
__global__ __launch_bounds__(256) void cvt_kernel(
    const float* __restrict__ q, const float* __restrict__ k,
    const float* __restrict__ v, const float* __restrict__ Wq,
    const float* __restrict__ Wk, const float* __restrict__ Wv,
    const float* __restrict__ Wp,
    ushort4* __restrict__ qkv_bf, ushort4* __restrict__ w_bf)
{
  int idx = blockIdx.x * 256 + threadIdx.x;
  const float* src; ushort4* dst; int i;
  if (idx < 3145728) {
    int which = idx >> 20; i = idx & 1048575;
    src = which == 0 ? q : which == 1 ? k : v;
    dst = qkv_bf + (size_t)which * 1048576 + i;
  } else {
    int w = idx - 3145728; int which = w >> 18; i = w & 262143;
    src = which == 0 ? Wq : which == 1 ? Wk : which == 2 ? Wv : Wp;
    dst = w_bf + w;
  }
  float4 val = ((const float4*)src)[i];
  union { ushort4 u; __hip_bfloat16 h[4]; } c;
  c.h[0] = __float2bfloat16(val.x); c.h[1] = __float2bfloat16(val.y);
  c.h[2] = __float2bfloat16(val.z); c.h[3] = __float2bfloat16(val.w);
  dst[0] = c.u;
}

// ------- bf16 NT GEMM tile: 128x128, K=1024, BK=64 (two 32-col halves) ----
// tailAtomic != nullptr: additionally atomicAdd per-column sums of rows with
// (rowInB + localRow) >= 80 into tailAtomic[col 0..127] (fp32, device scope).
__device__ __forceinline__ void gemm_tile128(
    const __hip_bfloat16* __restrict__ A, const __hip_bfloat16* __restrict__ Bw,
    __hip_bfloat16* __restrict__ C, float* tailAtomic, int rowInB)
{
  const int N = 1024, K = 1024;
  __shared__ __align__(16) __hip_bfloat16 As[2][128 * 32];
  __shared__ __align__(16) __hip_bfloat16 Bs[2][128 * 32];
  const int t = threadIdx.x;
  const int wv = t >> 6, lane = t & 63;
  const int wRow = (wv >> 1) * 64, wCol = (wv & 1) * 64;
  const int mrow = lane & 15, kq = lane >> 4;

  f32x4 acc[4][4] = {};

  for (int k0 = 0; k0 < K; k0 += 64) {
    __syncthreads();
#pragma unroll
    for (int half = 0; half < 2; ++half)
#pragma unroll
      for (int tI = 0; tI < 2; ++tI) {
        int chunk = wv * 2 + tI;              // 0..7, 1024B each within half
        int byteOff = chunk * 1024 + lane * 16;
        int row = byteOff >> 6;
        int colEl = (byteOff & 63) >> 1;
        const __hip_bfloat16* ga = A + (size_t)row * K + k0 + half * 32 + colEl;
        __builtin_amdgcn_global_load_lds(AS1((void*)ga), AS3(&As[half][chunk * 512]), 16, 0, 0);
        const __hip_bfloat16* gb = Bw + (size_t)row * K + k0 + half * 32 + colEl;
        __builtin_amdgcn_global_load_lds(AS1((void*)gb), AS3(&Bs[half][chunk * 512]), 16, 0, 0);
      }
    __syncthreads();

#pragma unroll
    for (int half = 0; half < 2; ++half) {
      bf16x8 af[4], bf[4];
#pragma unroll
      for (int mi = 0; mi < 4; ++mi)
        af[mi] = *(const bf16x8*)&As[half][(wRow + mi * 16 + mrow) * 32 + kq * 8];
#pragma unroll
      for (int ni = 0; ni < 4; ++ni)
        bf[ni] = *(const bf16x8*)&Bs[half][(wCol + ni * 16 + mrow) * 32 + kq * 8];
#pragma unroll
      for (int mi = 0; mi < 4; ++mi)
#pragma unroll
        for (int ni = 0; ni < 4; ++ni)
          acc[mi][ni] = __builtin_amdgcn_mfma_f32_16x16x32_bf16(af[mi], bf[ni], acc[mi][ni], 0, 0, 0);
    }
  }

  // C/D layout: col = lane&15, row = (lane>>4)*4 + r   [m89-verified]
#pragma unroll
  for (int mi = 0; mi < 4; ++mi)
#pragma unroll
    for (int ni = 0; ni < 4; ++ni)
#pragma unroll
      for (int r = 0; r < 4; ++r) {
        int row = wRow + mi * 16 + kq * 4 + r;
        int col = wCol + ni * 16 + mrow;
        C[(size_t)row * N + col] = __float2bfloat16(acc[mi][ni][r]);
      }

  if (tailAtomic) {   // wave-uniform branch (z==2 V blocks only)
#pragma unroll
    for (int ni = 0; ni < 4; ++ni) {
      float s = 0.0f;
#pragma unroll
      for (int mi = 0; mi < 4; ++mi)
#pragma unroll
        for (int r = 0; r < 4; ++r) {
          int localRow = rowInB + wRow + mi * 16 + kq * 4 + r;
          if (localRow >= 80) s += acc[mi][ni][r];
        }
      s += __shfl_xor(s, 16, 64);   // reduce across kq bit0
      s += __shfl_xor(s, 32, 64);   // reduce across kq bit1
      if (kq == 0) atomicAdd(&tailAtomic[wCol + ni * 16 + mrow], s);
    }
  }
}

// QKV: 768 blocks = 8n x (3z x 32m); m-consecutive within XCD for A-strip reuse.
// z==2 (V) blocks also accumulate tails[b][c] = sum_{j>=80} vp[b,j,c] via atomics.
__global__ __launch_bounds__(256) void qkv_gemm_kernel(
    const __hip_bfloat16* __restrict__ QKVbf, const __hip_bfloat16* __restrict__ Wbf,
    __hip_bfloat16* __restrict__ QKVp, float* __restrict__ tails)
{
  int l = blockIdx.x;            // 0..767
  int n = l / 96, mm = l % 96, z = mm >> 5, m = mm & 31;
  float* tailAtomic = nullptr;
  int rowInB = (m & 7) * 128;    // row offset within batch (8 m-tiles per b)
  if (z == 2) tailAtomic = tails + (size_t)(m >> 3) * 1024 + n * 128;
  gemm_tile128(
      QKVbf + (size_t)z * 4194304 + (size_t)m * 131072,
      Wbf + (size_t)z * 1048576 + (size_t)n * 131072,
      QKVp + (size_t)z * 4194304 + (size_t)m * 131072 + n * 128,
      tailAtomic, rowInB);
}

// ------- final GEMM: 64x64 tiles, 1024 blocks (4/CU), BK=64 ---------------
__global__ __launch_bounds__(256) void final_gemm_kernel(
    const __hip_bfloat16* __restrict__ Abf, const __hip_bfloat16* __restrict__ Wpbf,
    float* __restrict__ Out, const float* __restrict__ biasAll)
{
  const int N = 1024, K = 1024;
  int l = blockIdx.x;            // 0..1023
  int m = l & 63, n = l >> 6;    // m fastest -> XCD A-strip reuse
  const __hip_bfloat16* A = Abf + (size_t)m * 65536;      // 64 rows
  const __hip_bfloat16* Bw = Wpbf + (size_t)n * 65536;    // 64 rows
  float* C = Out + (size_t)m * 65536 + n * 64;
  const float* bias = biasAll + n * 64;

  __shared__ __align__(16) __hip_bfloat16 As[2][64 * 32];
  __shared__ __align__(16) __hip_bfloat16 Bs[2][64 * 32];
  const int t = threadIdx.x;
  const int wv = t >> 6, lane = t & 63;
  const int wRow = (wv >> 1) * 32, wCol = (wv & 1) * 32;
  const int mrow = lane & 15, kq = lane >> 4;

  f32x4 acc[2][2] = {};

  for (int k0 = 0; k0 < K; k0 += 64) {
    __syncthreads();
#pragma unroll
    for (int tI = 0; tI < 4; ++tI) {
      int c = wv * 4 + tI;                     // 0..15 chunks of 1024B
      int half, ch;
      const __hip_bfloat16* gsrc;
      __hip_bfloat16* ldst;
      if (c < 8) { half = c >> 2; ch = c & 3;
        int byteOff = ch * 1024 + lane * 16;
        gsrc = A + (size_t)(byteOff >> 6) * K + k0 + half * 32 + ((byteOff & 63) >> 1);
        ldst = &As[half][ch * 512];
      } else { int cb = c - 8; half = cb >> 2; ch = cb & 3;
        int byteOff = ch * 1024 + lane * 16;
        gsrc = Bw + (size_t)(byteOff >> 6) * K + k0 + half * 32 + ((byteOff & 63) >> 1);
        ldst = &Bs[half][ch * 512];
      }
      __builtin_amdgcn_global_load_lds(AS1((void*)gsrc), AS3(ldst), 16, 0, 0);
    }
    __syncthreads();

#pragma unroll
    for (int half = 0; half < 2; ++half) {
      bf16x8 af[2], bf[2];
#pragma unroll
      for (int mi = 0; mi < 2; ++mi)
        af[mi] = *(const bf16x8*)&As[half][(wRow + mi * 16 + mrow) * 32 + kq * 8];
#pragma unroll
      for (int ni = 0; ni < 2; ++ni)
        bf[ni] = *(const bf16x8*)&Bs[half][(wCol + ni * 16 + mrow) * 32 + kq * 8];
#pragma unroll
      for (int mi = 0; mi < 2; ++mi)
#pragma unroll
        for (int ni = 0; ni < 2; ++ni)
          acc[mi][ni] = __builtin_amdgcn_mfma_f32_16x16x32_bf16(af[mi], bf[ni], acc[mi][ni], 0, 0, 0);
    }
  }

#pragma unroll
  for (int mi = 0; mi < 2; ++mi)
#pragma unroll
    for (int ni = 0; ni < 2; ++ni)
#pragma unroll
      for (int r = 0; r < 4; ++r) {
        int row = wRow + mi * 16 + kq * 4 + r;
        int col = wCol + ni * 16 + mrow;
        C[(size_t)row * N + col] = acc[mi][ni][r] + bias[col];
      }
}

// ---------------- attention: per (b,h, 64-row i-tile) ---------------------
// LDS: bufA holds csl (f32 64x68) during phases A/B, then vpt (bf16 64x104)
// for phase D. wlb + scalars separate. ~30.4 KB total -> 4 blocks/CU.
__global__ __launch_bounds__(256) void attn_kernel(
    const __hip_bfloat16* __restrict__ QP, const __hip_bfloat16* __restrict__ KP,
    const __hip_bfloat16* __restrict__ VP, const float* __restrict__ tails,
    __hip_bfloat16* __restrict__ OUTA)
{
  const int b = blockIdx.z, h = blockIdx.y, i0 = blockIdx.x * 64;
  const int t = threadIdx.x, lane = t & 63, wv = t >> 6;

  __shared__ __align__(16) char bufA[64 * 68 * 4];      // csl f32 / vpt bf16 overlay
  float (*csl)[68] = (float(*)[68])bufA;                // inclusive cumsum
  __hip_bfloat16 (*vpt)[104] = (__hip_bfloat16(*)[104])bufA;  // vp^T B-operand
  __shared__ __align__(16) __hip_bfloat16 wlb[64][96];  // exp(wei-m), A-operand [i][j]
  __shared__ float scl[64], tlw[64], tail[64];

  if (t < 64) tail[t] = tails[(size_t)b * 1024 + h * 64 + t];

  // phase A: p = qp*kp/8, inclusive cumsum over d.
  // 4 threads per row, 16 elements each: vector loads + register cumsum +
  // 3-shuffle prefix across the 4-lane group + float4 stores.
  {
    const int i = t >> 2, seg = t & 3;
    const size_t base = ((size_t)(b * 1024 + i0 + i)) * 1024 + h * 64 + seg * 16;
    bf16x8 q0 = *(const bf16x8*)(QP + base);
    bf16x8 q1 = *(const bf16x8*)(QP + base + 8);
    bf16x8 k0 = *(const bf16x8*)(KP + base);
    bf16x8 k1 = *(const bf16x8*)(KP + base + 8);
    float cs[16];
    float run = 0.0f;
#pragma unroll
    for (int x = 0; x < 8; ++x) {
      run += (float)q0[x] * (float)k0[x] * 0.125f;
      cs[x] = run;
    }
#pragma unroll
    for (int x = 0; x < 8; ++x) {
      run += (float)q1[x] * (float)k1[x] * 0.125f;
      cs[8 + x] = run;
    }
    float t1 = __shfl_up(run, 1, 4);
    float t2 = __shfl_up(run, 2, 4);
    float t3 = __shfl_up(run, 3, 4);
    float off = 0.0f;
    if (seg > 0) off += t1;
    if (seg > 1) off += t2;
    if (seg > 2) off += t3;
    float4* dst = (float4*)&csl[i][seg * 16];
#pragma unroll
    for (int x4 = 0; x4 < 4; ++x4)
      dst[x4] = make_float4(cs[4 * x4] + off, cs[4 * x4 + 1] + off,
                            cs[4 * x4 + 2] + off, cs[4 * x4 + 3] + off);
  }
  __syncthreads();

  // phase B: wei for j<80, softmax max/sum (tail logit = 0, count 944)
  {
    int i = t >> 2, jg = t & 3;
    float wloc[20];
    float mx = 0.0f;  // includes tail's wei=0
#pragma unroll
    for (int q = 0; q < 20; ++q) {
      int j = jg + 4 * q;
      int s = j - 16; s = s < 0 ? 0 : s;
      int e = j + 16; e = e > 64 ? 64 : e;
      float w = csl[i][e - 1] - (s > 0 ? csl[i][s - 1] : 0.0f);
      wloc[q] = w;
      mx = fmaxf(mx, w);
    }
    mx = fmaxf(mx, __shfl_xor(mx, 1, 64));
    mx = fmaxf(mx, __shfl_xor(mx, 2, 64));
    float sum = 0.0f;
#pragma unroll
    for (int q = 0; q < 20; ++q) {
      float e_ = __expf(wloc[q] - mx);
      wlb[i][jg + 4 * q] = __float2bfloat16(e_);
      sum += e_;
    }
#pragma unroll
    for (int q = 0; q < 4; ++q)      // zero pad j = 80..95
      wlb[i][80 + jg + 4 * q] = __float2bfloat16(0.0f);
    sum += __shfl_xor(sum, 1, 64);
    sum += __shfl_xor(sum, 2, 64);
    float tw = __expf(-mx);
    sum += 944.0f * tw;
    if (jg == 0) { scl[i] = 1.0f / sum; tlw[i] = tw / sum; }
  }
  __syncthreads();   // all csl reads done -> safe to overlay with vpt

  // phase C: stage vp^T[d][j] for j<80; zero-pad j=80..95
  for (int idx = t; idx < 80 * 64; idx += 256) {
    int j = idx >> 6, d = idx & 63;
    vpt[d][j] = VP[((size_t)(b * 1024 + j)) * 1024 + h * 64 + d];
  }
  for (int idx = t; idx < 64 * 16; idx += 256) {
    int d = idx >> 4, j = 80 + (idx & 15);
    vpt[d][j] = __float2bfloat16(0.0f);
  }
  __syncthreads();

  // phase D: O[i][d] = sum_j wl[i][j] * vpt[d][j] via MFMA (M=64,N=64,K=96)
  {
    const int mh = (wv >> 1) * 32, nh = (wv & 1) * 32;
    const int mrow = lane & 15, kq = lane >> 4;
    f32x4 acc[2][2] = {};
#pragma unroll
    for (int k0 = 0; k0 < 96; k0 += 32) {
      bf16x8 af[2], bf[2];
#pragma unroll
      for (int mi = 0; mi < 2; ++mi)
        af[mi] = *(const bf16x8*)&wlb[mh + mi * 16 + mrow][k0 + kq * 8];
#pragma unroll
      for (int ni = 0; ni < 2; ++ni)
        bf[ni] = *(const bf16x8*)&vpt[nh + ni * 16 + mrow][k0 + kq * 8];
#pragma unroll
      for (int mi = 0; mi < 2; ++mi)
#pragma unroll
        for (int ni = 0; ni < 2; ++ni)
          acc[mi][ni] = __builtin_amdgcn_mfma_f32_16x16x32_bf16(af[mi], bf[ni], acc[mi][ni], 0, 0, 0);
    }
#pragma unroll
    for (int mi = 0; mi < 2; ++mi)
#pragma unroll
      for (int ni = 0; ni < 2; ++ni)
#pragma unroll
        for (int r = 0; r < 4; ++r) {
          int i = mh + mi * 16 + kq * 4 + r;
          int d = nh + ni * 16 + mrow;
          float o = acc[mi][ni][r] * scl[i] + tlw[i] * tail[d];
          OUTA[((size_t)(b * 1024 + i0 + i)) * 1024 + h * 64 + d] = __float2bfloat16(o);
        }
  }
}

// ---------------- launch ---------------------------------------------------
extern "C" void kernel_launch(void* const* d_in, const int* in_sizes, int n_in,
                              void* d_out, int out_size, void* d_ws, size_t ws_size,
                              hipStream_t stream)
{
  (void)in_sizes; (void)n_in; (void)out_size; (void)ws_size;
  const float* q  = (const float*)d_in[0];
  const float* k  = (const float*)d_in[1];
  const float* v  = (const float*)d_in[2];
  const float* Wq = (const float*)d_in[3];
  const float* Wk = (const float*)d_in[4];
  const float* Wv = (const float*)d_in[5];
  const float* Wp = (const float*)d_in[6];
  const float* bp = (const float*)d_in[7];

  char* ws = (char*)d_ws;
  __hip_bfloat16* qkv_bf = (__hip_bfloat16*)(ws);              // 24 MB (q,k,v bf16)
  __hip_bfloat16* w_bf   = (__hip_bfloat16*)(ws + 25165824);   // 8 MB (Wq,Wk,Wv,Wp)
  __hip_bfloat16* QKVp   = (__hip_bfloat16*)(ws + 33554432);   // 24 MB (qp,kp,vp bf16)
  __hip_bfloat16* OUTA   = (__hip_bfloat16*)(ws + 58720256);   // 8 MB
  float*          tails  = (float*)(ws + 67108864);            // 16 KB fp32
  float* out = (float*)d_out;

  hipMemsetAsync(tails, 0, 4096 * sizeof(float), stream);
  cvt_kernel<<<dim3(16384), 256, 0, stream>>>(q, k, v, Wq, Wk, Wv, Wp,
      (ushort4*)qkv_bf, (ushort4*)w_bf);
  qkv_gemm_kernel<<<dim3(768), 256, 0, stream>>>(qkv_bf, w_bf, QKVp, tails);
  attn_kernel<<<dim3(16, 16, 4), 256, 0, stream>>>(QKVp, QKVp + (size_t)4194304,
                                                   QKVp + (size_t)2 * 4194304, tails, OUTA);
  final_gemm_kernel<<<dim3(1024), 256, 0, stream>>>(OUTA, w_bf + (size_t)3 * 1048576,
                                                    out, bp);
}

// Round 8
// 175.314 us; speedup vs baseline: 1.3349x; 1.0146x over previous
//
#include <hip/hip_runtime.h>
#include <hip/hip_bf16.h>
#include <stdint.h>

// B=4, T=1024, C=1024, H=16, D=64, ks=16
// wei[b,h,i,j] = cs[i][e(j)] - cs[i][s(j)], s=clip(j-16,0,64), e=clip(j+16,0,64)
// => wei==0 for j>=80; softmax tail folds into one weight * tail-sum of vp.
// R8: memset folded into cvt (one fewer dispatch); non-temporal final stores.

typedef __bf16 bf16x8 __attribute__((ext_vector_type(8)));
typedef float f32x4 __attribute__((ext_vector_type(4)));

#define AS1(p) ((__attribute__((address_space(1))) void*)(p))
#define AS3(p) ((__attribute__((address_space(3))) void*)(p))

// ---------------- fused fp32 -> bf16 convert (float4 per thread) ----------
// flat: idx<3M -> q,k,v (1M float4 each); else -> Wq,Wk,Wv,Wp (256K each).
// Block 16384 zeroes the 4096-float tails buffer (replaces hipMemsetAsync;
// safe: qkv (consumer) is a later launch on the same stream).
__global__ __launch_bounds__(256) void cvt_kernel(
    const float* __restrict__ q, const float* __restrict__ k,
    const float* __restrict__ v, const float* __restrict__ Wq,
    const float* __restrict__ Wk, const float* __restrict__ Wv,
    const float* __restrict__ Wp,
    ushort4* __restrict__ qkv_bf, ushort4* __restrict__ w_bf,
    float* __restrict__ tails)
{
  if (blockIdx.x == 16384) {
    float4* tz = (float4*)tails;
    tz[threadIdx.x * 4 + 0] = make_float4(0.f, 0.f, 0.f, 0.f);
    tz[threadIdx.x * 4 + 1] = make_float4(0.f, 0.f, 0.f, 0.f);
    tz[threadIdx.x * 4 + 2] = make_float4(0.f, 0.f, 0.f, 0.f);
    tz[threadIdx.x * 4 + 3] = make_float4(0.f, 0.f, 0.f, 0.f);
    return;
  }
  int idx = blockIdx.x * 256 + threadIdx.x;
  const float* src; ushort4* dst; int i;
  if (idx < 3145728) {
    int which = idx >> 20; i = idx & 1048575;
    src = which == 0 ? q : which == 1 ? k : v;
    dst = qkv_bf + (size_t)which * 1048576 + i;
  } else {
    int w = idx - 3145728; int which = w >> 18; i = w & 262143;
    src = which == 0 ? Wq : which == 1 ? Wk : which == 2 ? Wv : Wp;
    dst = w_bf + w;
  }
  float4 val = ((const float4*)src)[i];
  union { ushort4 u; __hip_bfloat16 h[4]; } c;
  c.h[0] = __float2bfloat16(val.x); c.h[1] = __float2bfloat16(val.y);
  c.h[2] = __float2bfloat16(val.z); c.h[3] = __float2bfloat16(val.w);
  dst[0] = c.u;
}

// ------- bf16 NT GEMM tile: 128x128, K=1024, BK=64 (two 32-col halves) ----
// tailAtomic != nullptr: additionally atomicAdd per-column sums of rows with
// (rowInB + localRow) >= 80 into tailAtomic[col 0..127] (fp32, device scope).
__device__ __forceinline__ void gemm_tile128(
    const __hip_bfloat16* __restrict__ A, const __hip_bfloat16* __restrict__ Bw,
    __hip_bfloat16* __restrict__ C, float* tailAtomic, int rowInB)
{
  const int N = 1024, K = 1024;
  __shared__ __align__(16) __hip_bfloat16 As[2][128 * 32];
  __shared__ __align__(16) __hip_bfloat16 Bs[2][128 * 32];
  const int t = threadIdx.x;
  const int wv = t >> 6, lane = t & 63;
  const int wRow = (wv >> 1) * 64, wCol = (wv & 1) * 64;
  const int mrow = lane & 15, kq = lane >> 4;

  f32x4 acc[4][4] = {};

  for (int k0 = 0; k0 < K; k0 += 64) {
    __syncthreads();
#pragma unroll
    for (int half = 0; half < 2; ++half)
#pragma unroll
      for (int tI = 0; tI < 2; ++tI) {
        int chunk = wv * 2 + tI;              // 0..7, 1024B each within half
        int byteOff = chunk * 1024 + lane * 16;
        int row = byteOff >> 6;
        int colEl = (byteOff & 63) >> 1;
        const __hip_bfloat16* ga = A + (size_t)row * K + k0 + half * 32 + colEl;
        __builtin_amdgcn_global_load_lds(AS1((void*)ga), AS3(&As[half][chunk * 512]), 16, 0, 0);
        const __hip_bfloat16* gb = Bw + (size_t)row * K + k0 + half * 32 + colEl;
        __builtin_amdgcn_global_load_lds(AS1((void*)gb), AS3(&Bs[half][chunk * 512]), 16, 0, 0);
      }
    __syncthreads();

#pragma unroll
    for (int half = 0; half < 2; ++half) {
      bf16x8 af[4], bf[4];
#pragma unroll
      for (int mi = 0; mi < 4; ++mi)
        af[mi] = *(const bf16x8*)&As[half][(wRow + mi * 16 + mrow) * 32 + kq * 8];
#pragma unroll
      for (int ni = 0; ni < 4; ++ni)
        bf[ni] = *(const bf16x8*)&Bs[half][(wCol + ni * 16 + mrow) * 32 + kq * 8];
#pragma unroll
      for (int mi = 0; mi < 4; ++mi)
#pragma unroll
        for (int ni = 0; ni < 4; ++ni)
          acc[mi][ni] = __builtin_amdgcn_mfma_f32_16x16x32_bf16(af[mi], bf[ni], acc[mi][ni], 0, 0, 0);
    }
  }

  // C/D layout: col = lane&15, row = (lane>>4)*4 + r   [m89-verified]
#pragma unroll
  for (int mi = 0; mi < 4; ++mi)
#pragma unroll
    for (int ni = 0; ni < 4; ++ni)
#pragma unroll
      for (int r = 0; r < 4; ++r) {
        int row = wRow + mi * 16 + kq * 4 + r;
        int col = wCol + ni * 16 + mrow;
        C[(size_t)row * N + col] = __float2bfloat16(acc[mi][ni][r]);
      }

  if (tailAtomic) {   // wave-uniform branch (z==2 V blocks only)
#pragma unroll
    for (int ni = 0; ni < 4; ++ni) {
      float s = 0.0f;
#pragma unroll
      for (int mi = 0; mi < 4; ++mi)
#pragma unroll
        for (int r = 0; r < 4; ++r) {
          int localRow = rowInB + wRow + mi * 16 + kq * 4 + r;
          if (localRow >= 80) s += acc[mi][ni][r];
        }
      s += __shfl_xor(s, 16, 64);   // reduce across kq bit0
      s += __shfl_xor(s, 32, 64);   // reduce across kq bit1
      if (kq == 0) atomicAdd(&tailAtomic[wCol + ni * 16 + mrow], s);
    }
  }
}

// QKV: 768 blocks = 8n x (3z x 32m); m-consecutive within XCD for A-strip reuse.
// z==2 (V) blocks also accumulate tails[b][c] = sum_{j>=80} vp[b,j,c] via atomics.
__global__ __launch_bounds__(256) void qkv_gemm_kernel(
    const __hip_bfloat16* __restrict__ QKVbf, const __hip_bfloat16* __restrict__ Wbf,
    __hip_bfloat16* __restrict__ QKVp, float* __restrict__ tails)
{
  int l = blockIdx.x;            // 0..767
  int n = l / 96, mm = l % 96, z = mm >> 5, m = mm & 31;
  float* tailAtomic = nullptr;
  int rowInB = (m & 7) * 128;    // row offset within batch (8 m-tiles per b)
  if (z == 2) tailAtomic = tails + (size_t)(m >> 3) * 1024 + n * 128;
  gemm_tile128(
      QKVbf + (size_t)z * 4194304 + (size_t)m * 131072,
      Wbf + (size_t)z * 1048576 + (size_t)n * 131072,
      QKVp + (size_t)z * 4194304 + (size_t)m * 131072 + n * 128,
      tailAtomic, rowInB);
}

// ------- final GEMM: 64x64 tiles, 1024 blocks (4/CU), BK=64 ---------------
__global__ __launch_bounds__(256) void final_gemm_kernel(
    const __hip_bfloat16* __restrict__ Abf, const __hip_bfloat16* __restrict__ Wpbf,
    float* __restrict__ Out, const float* __restrict__ biasAll)
{
  const int N = 1024, K = 1024;
  int l = blockIdx.x;            // 0..1023
  int m = l & 63, n = l >> 6;    // m fastest -> XCD A-strip reuse
  const __hip_bfloat16* A = Abf + (size_t)m * 65536;      // 64 rows
  const __hip_bfloat16* Bw = Wpbf + (size_t)n * 65536;    // 64 rows
  float* C = Out + (size_t)m * 65536 + n * 64;
  const float* bias = biasAll + n * 64;

  __shared__ __align__(16) __hip_bfloat16 As[2][64 * 32];
  __shared__ __align__(16) __hip_bfloat16 Bs[2][64 * 32];
  const int t = threadIdx.x;
  const int wv = t >> 6, lane = t & 63;
  const int wRow = (wv >> 1) * 32, wCol = (wv & 1) * 32;
  const int mrow = lane & 15, kq = lane >> 4;

  f32x4 acc[2][2] = {};

  for (int k0 = 0; k0 < K; k0 += 64) {
    __syncthreads();
#pragma unroll
    for (int tI = 0; tI < 4; ++tI) {
      int c = wv * 4 + tI;                     // 0..15 chunks of 1024B
      int half, ch;
      const __hip_bfloat16* gsrc;
      __hip_bfloat16* ldst;
      if (c < 8) { half = c >> 2; ch = c & 3;
        int byteOff = ch * 1024 + lane * 16;
        gsrc = A + (size_t)(byteOff >> 6) * K + k0 + half * 32 + ((byteOff & 63) >> 1);
        ldst = &As[half][ch * 512];
      } else { int cb = c - 8; half = cb >> 2; ch = cb & 3;
        int byteOff = ch * 1024 + lane * 16;
        gsrc = Bw + (size_t)(byteOff >> 6) * K + k0 + half * 32 + ((byteOff & 63) >> 1);
        ldst = &Bs[half][ch * 512];
      }
      __builtin_amdgcn_global_load_lds(AS1((void*)gsrc), AS3(ldst), 16, 0, 0);
    }
    __syncthreads();

#pragma unroll
    for (int half = 0; half < 2; ++half) {
      bf16x8 af[2], bf[2];
#pragma unroll
      for (int mi = 0; mi < 2; ++mi)
        af[mi] = *(const bf16x8*)&As[half][(wRow + mi * 16 + mrow) * 32 + kq * 8];
#pragma unroll
      for (int ni = 0; ni < 2; ++ni)
        bf[ni] = *(const bf16x8*)&Bs[half][(wCol + ni * 16 + mrow) * 32 + kq * 8];
#pragma unroll
      for (int mi = 0; mi < 2; ++mi)
#pragma unroll
        for (int ni = 0; ni < 2; ++ni)
          acc[mi][ni] = __builtin_amdgcn_mfma_f32_16x16x32_bf16(af[mi], bf[ni], acc[mi][ni], 0, 0, 0);
    }
  }

#pragma unroll
  for (int mi = 0; mi < 2; ++mi)
#pragma unroll
    for (int ni = 0; ni < 2; ++ni)
#pragma unroll
      for (int r = 0; r < 4; ++r) {
        int row = wRow + mi * 16 + kq * 4 + r;
        int col = wCol + ni * 16 + mrow;
        // out is never re-read on device: bypass L2 with non-temporal store
        __builtin_nontemporal_store(acc[mi][ni][r] + bias[col],
                                    &C[(size_t)row * N + col]);
      }
}

// ---------------- attention: per (b,h, 64-row i-tile) ---------------------
// LDS: bufA holds csl (f32 64x68) during phases A/B, then vpt (bf16 64x104)
// for phase D. wlb + scalars separate. ~30.4 KB total -> 4 blocks/CU.
__global__ __launch_bounds__(256) void attn_kernel(
    const __hip_bfloat16* __restrict__ QP, const __hip_bfloat16* __restrict__ KP,
    const __hip_bfloat16* __restrict__ VP, const float* __restrict__ tails,
    __hip_bfloat16* __restrict__ OUTA)
{
  const int b = blockIdx.z, h = blockIdx.y, i0 = blockIdx.x * 64;
  const int t = threadIdx.x, lane = t & 63, wv = t >> 6;

  __shared__ __align__(16) char bufA[64 * 68 * 4];      // csl f32 / vpt bf16 overlay
  float (*csl)[68] = (float(*)[68])bufA;                // inclusive cumsum
  __hip_bfloat16 (*vpt)[104] = (__hip_bfloat16(*)[104])bufA;  // vp^T B-operand
  __shared__ __align__(16) __hip_bfloat16 wlb[64][96];  // exp(wei-m), A-operand [i][j]
  __shared__ float scl[64], tlw[64], tail[64];

  if (t < 64) tail[t] = tails[(size_t)b * 1024 + h * 64 + t];

  // phase A: p = qp*kp/8, inclusive cumsum over d.
  // 4 threads per row, 16 elements each: vector loads + register cumsum +
  // 3-shuffle prefix across the 4-lane group + float4 stores.
  {
    const int i = t >> 2, seg = t & 3;
    const size_t base = ((size_t)(b * 1024 + i0 + i)) * 1024 + h * 64 + seg * 16;
    bf16x8 q0 = *(const bf16x8*)(QP + base);
    bf16x8 q1 = *(const bf16x8*)(QP + base + 8);
    bf16x8 k0 = *(const bf16x8*)(KP + base);
    bf16x8 k1 = *(const bf16x8*)(KP + base + 8);
    float cs[16];
    float run = 0.0f;
#pragma unroll
    for (int x = 0; x < 8; ++x) {
      run += (float)q0[x] * (float)k0[x] * 0.125f;
      cs[x] = run;
    }
#pragma unroll
    for (int x = 0; x < 8; ++x) {
      run += (float)q1[x] * (float)k1[x] * 0.125f;
      cs[8 + x] = run;
    }
    float t1 = __shfl_up(run, 1, 4);
    float t2 = __shfl_up(run, 2, 4);
    float t3 = __shfl_up(run, 3, 4);
    float off = 0.0f;
    if (seg > 0) off += t1;
    if (seg > 1) off += t2;
    if (seg > 2) off += t3;
    float4* dst = (float4*)&csl[i][seg * 16];
#pragma unroll
    for (int x4 = 0; x4 < 4; ++x4)
      dst[x4] = make_float4(cs[4 * x4] + off, cs[4 * x4 + 1] + off,
                            cs[4 * x4 + 2] + off, cs[4 * x4 + 3] + off);
  }
  __syncthreads();

  // phase B: wei for j<80, softmax max/sum (tail logit = 0, count 944)
  {
    int i = t >> 2, jg = t & 3;
    float wloc[20];
    float mx = 0.0f;  // includes tail's wei=0
#pragma unroll
    for (int q = 0; q < 20; ++q) {
      int j = jg + 4 * q;
      int s = j - 16; s = s < 0 ? 0 : s;
      int e = j + 16; e = e > 64 ? 64 : e;
      float w = csl[i][e - 1] - (s > 0 ? csl[i][s - 1] : 0.0f);
      wloc[q] = w;
      mx = fmaxf(mx, w);
    }
    mx = fmaxf(mx, __shfl_xor(mx, 1, 64));
    mx = fmaxf(mx, __shfl_xor(mx, 2, 64));
    float sum = 0.0f;
#pragma unroll
    for (int q = 0; q < 20; ++q) {
      float e_ = __expf(wloc[q] - mx);
      wlb[i][jg + 4 * q] = __float2bfloat16(e_);
      sum += e_;
    }
#pragma unroll
    for (int q = 0; q < 4; ++q)      // zero pad j = 80..95
      wlb[i][80 + jg + 4 * q] = __float2bfloat16(0.0f);
    sum += __shfl_xor(sum, 1, 64);
    sum += __shfl_xor(sum, 2, 64);
    float tw = __expf(-mx);
    sum += 944.0f * tw;
    if (jg == 0) { scl[i] = 1.0f / sum; tlw[i] = tw / sum; }
  }
  __syncthreads();   // all csl reads done -> safe to overlay with vpt

  // phase C: stage vp^T[d][j] for j<80; zero-pad j=80..95
  for (int idx = t; idx < 80 * 64; idx += 256) {
    int j = idx >> 6, d = idx & 63;
    vpt[d][j] = VP[((size_t)(b * 1024 + j)) * 1024 + h * 64 + d];
  }
  for (int idx = t; idx < 64 * 16; idx += 256) {
    int d = idx >> 4, j = 80 + (idx & 15);
    vpt[d][j] = __float2bfloat16(0.0f);
  }
  __syncthreads();

  // phase D: O[i][d] = sum_j wl[i][j] * vpt[d][j] via MFMA (M=64,N=64,K=96)
  {
    const int mh = (wv >> 1) * 32, nh = (wv & 1) * 32;
    const int mrow = lane & 15, kq = lane >> 4;
    f32x4 acc[2][2] = {};
#pragma unroll
    for (int k0 = 0; k0 < 96; k0 += 32) {
      bf16x8 af[2], bf[2];
#pragma unroll
      for (int mi = 0; mi < 2; ++mi)
        af[mi] = *(const bf16x8*)&wlb[mh + mi * 16 + mrow][k0 + kq * 8];
#pragma unroll
      for (int ni = 0; ni < 2; ++ni)
        bf[ni] = *(const bf16x8*)&vpt[nh + ni * 16 + mrow][k0 + kq * 8];
#pragma unroll
      for (int mi = 0; mi < 2; ++mi)
#pragma unroll
        for (int ni = 0; ni < 2; ++ni)
          acc[mi][ni] = __builtin_amdgcn_mfma_f32_16x16x32_bf16(af[mi], bf[ni], acc[mi][ni], 0, 0, 0);
    }
#pragma unroll
    for (int mi = 0; mi < 2; ++mi)
#pragma unroll
      for (int ni = 0; ni < 2; ++ni)
#pragma unroll
        for (int r = 0; r < 4; ++r) {
          int i = mh + mi * 16 + kq * 4 + r;
          int d = nh + ni * 16 + mrow;
          float o = acc[mi][ni][r] * scl[i] + tlw[i] * tail[d];
          OUTA[((size_t)(b * 1024 + i0 + i)) * 1024 + h * 64 + d] = __float2bfloat16(o);
        }
  }
}

// ---------------- launch ---------------------------------------------------
extern "C" void kernel_launch(void* const* d_in, const int* in_sizes, int n_in,
                              void* d_out, int out_size, void* d_ws, size_t ws_size,
                              hipStream_t stream)
{
  (void)in_sizes; (void)n_in; (void)out_size; (void)ws_size;
  const float* q  = (const float*)d_in[0];
  const float* k  = (const float*)d_in[1];
  const float* v  = (const float*)d_in[2];
  const float* Wq = (const float*)d_in[3];
  const float* Wk = (const float*)d_in[4];
  const float* Wv = (const float*)d_in[5];
  const float* Wp = (const float*)d_in[6];
  const float* bp = (const float*)d_in[7];

  char* ws = (char*)d_ws;
  __hip_bfloat16* qkv_bf = (__hip_bfloat16*)(ws);              // 24 MB (q,k,v bf16)
  __hip_bfloat16* w_bf   = (__hip_bfloat16*)(ws + 25165824);   // 8 MB (Wq,Wk,Wv,Wp)
  __hip_bfloat16* QKVp   = (__hip_bfloat16*)(ws + 33554432);   // 24 MB (qp,kp,vp bf16)
  __hip_bfloat16* OUTA   = (__hip_bfloat16*)(ws + 58720256);   // 8 MB
  float*          tails  = (float*)(ws + 67108864);            // 16 KB fp32
  float* out = (float*)d_out;

  cvt_kernel<<<dim3(16385), 256, 0, stream>>>(q, k, v, Wq, Wk, Wv, Wp,
      (ushort4*)qkv_bf, (ushort4*)w_bf, tails);
  qkv_gemm_kernel<<<dim3(768), 256, 0, stream>>>(qkv_bf, w_bf, QKVp, tails);
  attn_kernel<<<dim3(16, 16, 4), 256, 0, stream>>>(QKVp, QKVp + (size_t)4194304,
                                                   QKVp + (size_t)2 * 4194304, tails, OUTA);
  final_gemm_kernel<<<dim3(1024), 256, 0, stream>>>(OUTA, w_bf + (size_t)3 * 1048576,
                                                    out, bp);
}